// Round 8
// baseline (4553.832 us; speedup 1.0000x reference)
//
#include <hip/hip_runtime.h>
#include <cstdint>
#include <cstdio>

#define B_ 4
#define S_ 2048
#define H_ 1024
#define M_ 512
#define NH_ 16
#define HD_ 64

// ---------------------------------------------------------------------------
// fp32 VALU GEMM: C[Mrows,N] = act(A[Mrows,K] @ B[K,N] + bias)
// B read directly as (K,N) row-major. A split at asplit between A1/A2
// (virtual concat for combined = [hs | attended]).
// 64x64 tile, BK=32, 256 threads, 4x4 micro-tile per thread.
// ---------------------------------------------------------------------------
#define FBM 64
#define FBN 64
#define FBK 32

__global__ __launch_bounds__(256) void gemm_f32(
    const float* __restrict__ A1, const float* __restrict__ A2, int asplit,
    const float* __restrict__ Bm, const float* __restrict__ bias,
    float* __restrict__ C, int Mrows, int Ndim, int K, int act_gelu)
{
  __shared__ float Ast[FBK][FBM + 4];
  __shared__ float Bst[FBK][FBN + 4];
  const int t = threadIdx.x;
  const int tx = t & 15, ty = t >> 4;
  const int bm = blockIdx.x * FBM, bn = blockIdx.y * FBN;

  float acc[4][4];
  #pragma unroll
  for (int i = 0; i < 4; i++)
    #pragma unroll
    for (int j = 0; j < 4; j++) acc[i][j] = 0.f;

  for (int k0 = 0; k0 < K; k0 += FBK) {
    {
      const int r = t >> 2, kc = (t & 3) * 8;
      const int kg = k0 + kc;            // 8-chunks never straddle asplit
      const float* src = (kg < asplit)
          ? A1 + (size_t)(bm + r) * asplit + kg
          : A2 + (size_t)(bm + r) * (K - asplit) + (kg - asplit);
      float4 p0 = *(const float4*)src;
      float4 p1 = *(const float4*)(src + 4);
      Ast[kc + 0][r] = p0.x; Ast[kc + 1][r] = p0.y;
      Ast[kc + 2][r] = p0.z; Ast[kc + 3][r] = p0.w;
      Ast[kc + 4][r] = p1.x; Ast[kc + 5][r] = p1.y;
      Ast[kc + 6][r] = p1.z; Ast[kc + 7][r] = p1.w;
    }
    #pragma unroll
    for (int it = 0; it < 2; it++) {
      const int kr = (t >> 4) + it * 16;
      const int c4 = (t & 15) * 4;
      *(float4*)&Bst[kr][c4] = *(const float4*)&Bm[(size_t)(k0 + kr) * Ndim + bn + c4];
    }
    __syncthreads();
    #pragma unroll 4
    for (int kk = 0; kk < FBK; kk++) {
      float4 av = *(const float4*)&Ast[kk][ty * 4];
      float4 bv = *(const float4*)&Bst[kk][tx * 4];
      float aa[4] = {av.x, av.y, av.z, av.w};
      float bb[4] = {bv.x, bv.y, bv.z, bv.w};
      #pragma unroll
      for (int i = 0; i < 4; i++)
        #pragma unroll
        for (int j = 0; j < 4; j++)
          acc[i][j] += aa[i] * bb[j];
    }
    __syncthreads();
  }

  #pragma unroll
  for (int j = 0; j < 4; j++) {
    int col = bn + tx * 4 + j;
    float bvv = bias[col];
    #pragma unroll
    for (int i = 0; i < 4; i++) {
      int row = bm + ty * 4 + i;
      float v = acc[i][j] + bvv;
      if (act_gelu) v = 0.5f * v * (1.f + erff(v * 0.70710678f)); // exact gelu
      C[(size_t)row * Ndim + col] = v;
    }
  }
}

// ---------------------------------------------------------------------------
// Attention (fp32): one block per (b, s) row; loop over 16 heads.
// ---------------------------------------------------------------------------
__global__ __launch_bounds__(256) void attn_k(
    const float* __restrict__ qb, const float* __restrict__ kb,
    const float* __restrict__ vb, const int* __restrict__ mask,
    float* __restrict__ att, float* __restrict__ memo)
{
  __shared__ float qs[H_];
  __shared__ float sm[M_];
  __shared__ float red[256];
  __shared__ float oacc4[4][64];

  const int t = threadIdx.x;
  const int b = blockIdx.x >> 11;
  const int s = blockIdx.x & 2047;

  #pragma unroll
  for (int i = 0; i < 4; i++) {
    int c = t + i * 256;
    qs[c] = qb[(size_t)(b * S_ + s) * H_ + c];
  }
  __syncthreads();

  const int mk0 = mask[b * M_ + t];
  const int mk1 = mask[b * M_ + t + 256];
  float macc0 = 0.f, macc1 = 0.f;

  for (int n = 0; n < NH_; n++) {
    float l0 = 0.f, l1 = 0.f;
    const float* k0r = kb + ((size_t)(b * M_ + t) * NH_ + n) * HD_;
    const float* k1r = kb + ((size_t)(b * M_ + t + 256) * NH_ + n) * HD_;
    #pragma unroll
    for (int d4 = 0; d4 < 64; d4 += 4) {
      float4 ka = *(const float4*)(k0r + d4);
      float4 kc = *(const float4*)(k1r + d4);
      float4 qv = *(const float4*)&qs[n * 64 + d4];
      l0 += qv.x * ka.x + qv.y * ka.y + qv.z * ka.z + qv.w * ka.w;
      l1 += qv.x * kc.x + qv.y * kc.y + qv.z * kc.z + qv.w * kc.w;
    }
    l0 = mk0 ? l0 * 0.125f : -1e30f;   // 1/sqrt(64)
    l1 = mk1 ? l1 * 0.125f : -1e30f;

    red[t] = fmaxf(l0, l1);
    __syncthreads();
    for (int st = 128; st > 0; st >>= 1) {
      if (t < st) red[t] = fmaxf(red[t], red[t + st]);
      __syncthreads();
    }
    const float rmax = red[0];
    __syncthreads();

    const float e0 = expf(l0 - rmax);
    const float e1 = expf(l1 - rmax);
    red[t] = e0 + e1;
    __syncthreads();
    for (int st = 128; st > 0; st >>= 1) {
      if (t < st) red[t] += red[t + st];
      __syncthreads();
    }
    const float inv = 1.f / red[0];
    __syncthreads();

    const float w0 = e0 * inv, w1 = e1 * inv;
    sm[t] = w0;
    sm[t + 256] = w1;
    macc0 += w0 * (1.f / 16.f);
    macc1 += w1 * (1.f / 16.f);
    __syncthreads();

    const int d = t & 63, mq = t >> 6;
    float a = 0.f;
    #pragma unroll 4
    for (int mi = 0; mi < 128; mi++) {
      int m = mq * 128 + mi;
      a += sm[m] * vb[((size_t)(b * M_ + m) * NH_ + n) * HD_ + d];
    }
    oacc4[mq][d] = a;
    __syncthreads();
    if (t < 64) {
      float r = oacc4[0][t] + oacc4[1][t] + oacc4[2][t] + oacc4[3][t];
      att[(size_t)(b * S_ + s) * H_ + n * HD_ + t] = r;
    }
    __syncthreads();
  }

  memo[(size_t)(b * S_ + s) * M_ + t] = macc0;
  memo[(size_t)(b * S_ + s) * M_ + t + 256] = macc1;
}

// ---------------------------------------------------------------------------
// Final: gate = sigmoid(g1 . Wg2 + bg2); LN(fp); blend with hs. fp32 out.
// ---------------------------------------------------------------------------
__global__ __launch_bounds__(256) void final_k(
    const float* __restrict__ g1, const float* __restrict__ wg2,
    const float* __restrict__ bg2, const float* __restrict__ fp,
    const float* __restrict__ hs, const float* __restrict__ lngm,
    const float* __restrict__ lnbv, float* __restrict__ out)
{
  __shared__ float red[3][256];
  const int r = blockIdx.x, t = threadIdx.x;
  float x[4]; float dotp = 0.f, s1 = 0.f, s2 = 0.f;
  #pragma unroll
  for (int i = 0; i < 4; i++) {
    int c = t + i * 256;
    dotp += g1[(size_t)r * H_ + c] * wg2[c];
    float fv = fp[(size_t)r * H_ + c];
    x[i] = fv; s1 += fv; s2 += fv * fv;
  }
  red[0][t] = dotp; red[1][t] = s1; red[2][t] = s2;
  __syncthreads();
  for (int s = 128; s > 0; s >>= 1) {
    if (t < s) {
      red[0][t] += red[0][t + s];
      red[1][t] += red[1][t + s];
      red[2][t] += red[2][t + s];
    }
    __syncthreads();
  }
  const float gate = 1.f / (1.f + expf(-(red[0][0] + bg2[0])));
  const float mu = red[1][0] * (1.f / 1024.f);
  const float var = red[2][0] * (1.f / 1024.f) - mu * mu;
  const float rs = rsqrtf(var + 1e-5f);
  #pragma unroll
  for (int i = 0; i < 4; i++) {
    int c = t + i * 256;
    float fused = (x[i] - mu) * rs * lngm[c] + lnbv[c];
    float hv = hs[(size_t)r * H_ + c];
    out[(size_t)r * H_ + c] = gate * fused + (1.f - gate) * hv;
  }
}

// ---------------------------------------------------------------------------
extern "C" void kernel_launch(void* const* d_in, const int* in_sizes, int n_in,
                              void* d_out, int out_size, void* d_ws, size_t ws_size,
                              hipStream_t stream) {
  const float* hs   = (const float*)d_in[0];
  const float* memb = (const float*)d_in[1];
  const int*   mask = (const int*)d_in[2];
  // d_in[3] surprise_score: unused (w*(1+s)/sum(w*(1+s)) == w identically)
  const float* Wq  = (const float*)d_in[4];  const float* bq  = (const float*)d_in[5];
  const float* Wk  = (const float*)d_in[6];  const float* bk  = (const float*)d_in[7];
  const float* Wv  = (const float*)d_in[8];  const float* bv  = (const float*)d_in[9];
  const float* W1  = (const float*)d_in[10]; const float* b1  = (const float*)d_in[11];
  const float* W2  = (const float*)d_in[12]; const float* b2  = (const float*)d_in[13];
  const float* lng = (const float*)d_in[14]; const float* lnb = (const float*)d_in[15];
  const float* Wg1 = (const float*)d_in[16]; const float* bg1 = (const float*)d_in[17];
  const float* Wg2 = (const float*)d_in[18]; const float* bg2 = (const float*)d_in[19];

  char* ws = (char*)d_ws;
  size_t o = 0;
  auto alloc = [&](size_t bytes) {
    char* p = ws + o; o += (bytes + 255) & ~(size_t)255; return p;
  };
  float* qbuf = (float*)alloc((size_t)8388608 * 4);
  float* kbuf = (float*)alloc((size_t)2097152 * 4);
  float* vbuf = (float*)alloc((size_t)2097152 * 4);
  float* attb = (float*)alloc((size_t)8388608 * 4);
  float* h1b  = (float*)alloc((size_t)8388608 * 4);
  float* g1b  = (float*)alloc((size_t)8388608 * 4);
  float* fpb  = qbuf;  // reuse: q dead after attention (stream-ordered)
  if (o > ws_size) { fprintf(stderr, "ws too small: %zu > %zu\n", o, ws_size); return; }

  float* out  = (float*)d_out;                      // fp32 output!
  float* memo = out + (size_t)B_ * S_ * H_;         // mem_attn, fp32

  // --- projections: A @ W, W read directly as (K,N) ---
  gemm_f32<<<dim3(128, 16), 256, 0, stream>>>(hs, hs, 1024, Wq, bq, qbuf, 8192, 1024, 1024, 0);
  gemm_f32<<<dim3(32, 16),  256, 0, stream>>>(memb, memb, 256, Wk, bk, kbuf, 2048, 1024, 256, 0);
  gemm_f32<<<dim3(32, 16),  256, 0, stream>>>(memb, memb, 256, Wv, bv, vbuf, 2048, 1024, 256, 0);

  // --- attention + mem_attn ---
  attn_k<<<dim3(8192), 256, 0, stream>>>(qbuf, kbuf, vbuf, mask, attb, memo);

  // --- MLP + gate branch (combined = [hs | attended] via split-A) ---
  gemm_f32<<<dim3(128, 16), 256, 0, stream>>>(hs, attb, 1024, W1, b1, h1b, 8192, 1024, 2048, 1);
  gemm_f32<<<dim3(128, 16), 256, 0, stream>>>(hs, attb, 1024, Wg1, bg1, g1b, 8192, 1024, 2048, 1);
  gemm_f32<<<dim3(128, 16), 256, 0, stream>>>(h1b, h1b, 1024, W2, b2, fpb, 8192, 1024, 1024, 0);

  // --- gate + layernorm + blend ---
  final_k<<<dim3(8192), 256, 0, stream>>>(g1b, Wg2, bg2, fpb, hs, lng, lnb, out);
}